// Round 8
// baseline (259.566 us; speedup 1.0000x reference)
//
#include <hip/hip_runtime.h>

#define RS2f 0.70710678118654752f
#define KHALF 0.07957747154594767f   // 0.5/(2*pi): half-angle, revolutions

// DPP quad_perm encodings
#define QP_XOR1 0xB1   // [1,0,3,2]
#define QP_XOR2 0x4E   // [2,3,0,1]
#define QP_BC0  0x00
#define QP_BC1  0x55
#define QP_BC2  0xAA
#define QP_BC3  0xFF

typedef float v2f __attribute__((ext_vector_type(2)));
typedef float v4f __attribute__((ext_vector_type(4)));
typedef v4f v4fu __attribute__((aligned(4)));

template<int CTRL> __device__ __forceinline__ float dppf(float x) {
  return __int_as_float(__builtin_amdgcn_update_dpp(
      0, __float_as_int(x), CTRL, 0xF, 0xF, true));
}
template<int CTRL> __device__ __forceinline__ v2f dpp2(v2f v) {
  v2f r; r.x = dppf<CTRL>(v.x); r.y = dppf<CTRL>(v.y); return r;
}
// cross-quad exchange lane^4 (ds_swizzle BitMode xor=4) — verified r1
__device__ __forceinline__ float swz4(float x) {
  return __int_as_float(__builtin_amdgcn_ds_swizzle(__float_as_int(x), 0x101F));
}
__device__ __forceinline__ v2f swz4v(v2f v) { v2f r; r.x = swz4(v.x); r.y = swz4(v.y); return r; }
__device__ __forceinline__ float sxor(float x, int m) { return __int_as_float(__float_as_int(x) ^ m); }
__device__ __forceinline__ v2f sxor2(v2f v, int m) { v2f r; r.x = sxor(v.x, m); r.y = sxor(v.y, m); return r; }
__device__ __forceinline__ v4f loadu4(const float* p) { return *(const v4fu*)p; }

#define DX1(v) dpp2<QP_XOR1>(v)
#define DX2(v) dpp2<QP_XOR2>(v)
#define SWZ(v) swz4v(v)

// ---- packed fp32 (each op: .x = image0, .y = image1) ----
__device__ __forceinline__ v2f pk_fma2(v2f a, v2f b, v2f c) {
  v2f d; asm("v_pk_fma_f32 %0, %1, %2, %3 op_sel:[0,0,0] op_sel_hi:[1,1,1]"
             : "=v"(d) : "v"(a), "v"(b), "v"(c)); return d;
}
__device__ __forceinline__ v2f pk_fma2n(v2f a, v2f b, v2f c) {  // -a*b + c
  v2f d; asm("v_pk_fma_f32 %0, %1, %2, %3 op_sel:[0,0,0] op_sel_hi:[1,1,1] neg_lo:[1,0,0] neg_hi:[1,0,0]"
             : "=v"(d) : "v"(a), "v"(b), "v"(c)); return d;
}
__device__ __forceinline__ v2f pk_mul2(v2f a, v2f b) {
  v2f d; asm("v_pk_mul_f32 %0, %1, %2 op_sel:[0,0] op_sel_hi:[1,1]"
             : "=v"(d) : "v"(a), "v"(b)); return d;
}
__device__ __forceinline__ v2f pk_mul2n(v2f a, v2f b) {         // -a*b
  v2f d; asm("v_pk_mul_f32 %0, %1, %2 op_sel:[0,0] op_sel_hi:[1,1] neg_lo:[1,0] neg_hi:[1,0]"
             : "=v"(d) : "v"(a), "v"(b)); return d;
}
__device__ __forceinline__ v2f pk_add2(v2f a, v2f b) {
  v2f d; asm("v_pk_add_f32 %0, %1, %2 op_sel:[0,0] op_sel_hi:[1,1]"
             : "=v"(d) : "v"(a), "v"(b)); return d;
}
__device__ __forceinline__ v2f pk_sub2(v2f a, v2f b) {          // a - b
  v2f d; asm("v_pk_add_f32 %0, %1, %2 op_sel:[0,0] op_sel_hi:[1,1] neg_lo:[0,1] neg_hi:[0,1]"
             : "=v"(d) : "v"(a), "v"(b)); return d;
}
// scalar-pair coefficient ops: coef c = (lo,hi), broadcast one half to both lanes
__device__ __forceinline__ v2f pk_fma_rlo(v2f c, v2f x, v2f acc) {  // c.lo*x + acc
  v2f d; asm("v_pk_fma_f32 %0, %1, %2, %3 op_sel:[0,0,0] op_sel_hi:[0,1,1]"
             : "=v"(d) : "v"(c), "v"(x), "v"(acc)); return d;
}
__device__ __forceinline__ v2f pk_fma_rhi(v2f c, v2f x, v2f acc) {  // c.hi*x + acc
  v2f d; asm("v_pk_fma_f32 %0, %1, %2, %3 op_sel:[1,0,0] op_sel_hi:[1,1,1]"
             : "=v"(d) : "v"(c), "v"(x), "v"(acc)); return d;
}
__device__ __forceinline__ v2f pk_mul_rlo(v2f c, v2f x) {           // c.lo*x
  v2f d; asm("v_pk_mul_f32 %0, %1, %2 op_sel:[0,0] op_sel_hi:[0,1]"
             : "=v"(d) : "v"(c), "v"(x)); return d;
}
__device__ __forceinline__ v2f pk_mul_rhi(v2f c, v2f x) {           // c.hi*x
  v2f d; asm("v_pk_mul_f32 %0, %1, %2 op_sel:[1,0] op_sel_hi:[1,1]"
             : "=v"(d) : "v"(c), "v"(x)); return d;
}
__device__ __forceinline__ v2f pk_mul_nrhi(v2f c, v2f x) {          // -c.hi*x
  v2f d; asm("v_pk_mul_f32 %0, %1, %2 op_sel:[1,0] op_sel_hi:[1,1] neg_lo:[1,0] neg_hi:[1,0]"
             : "=v"(d) : "v"(c), "v"(x)); return d;
}

// scalar half-angle sincos (constants setup only)
__device__ __forceinline__ void hsc(float x, float* s, float* c) {
  float t = x * KHALF;
  *s = __builtin_amdgcn_sinf(t);
  *c = __builtin_amdgcn_cosf(t);
}

// ---- packed gate build: row0 of U = RZ(a4)RY(a3)RZ(a2)RY(a1)RZ(a0)·H ----
// (math verified r8-scalar; mechanical packed transcription)
#define BUILD_T_P                                                            \
  v2f sBp, cBp, sBm, cBm, sC_, cC_, sP_, cP_, sM_, cM_;                      \
  { v2f tBp = pk_mul2(pk_add2(a1, a3), KK);                                  \
    v2f tBm = pk_mul2(pk_sub2(a1, a3), KK);                                  \
    v2f tC  = pk_mul2(a2, KK);                                               \
    v2f tP  = pk_mul2(pk_add2(a0, a4), KK);                                  \
    v2f tM  = pk_mul2(pk_sub2(a0, a4), KK);                                  \
    sBp.x = __builtin_amdgcn_sinf(tBp.x); sBp.y = __builtin_amdgcn_sinf(tBp.y); \
    cBp.x = __builtin_amdgcn_cosf(tBp.x); cBp.y = __builtin_amdgcn_cosf(tBp.y); \
    sBm.x = __builtin_amdgcn_sinf(tBm.x); sBm.y = __builtin_amdgcn_sinf(tBm.y); \
    cBm.x = __builtin_amdgcn_cosf(tBm.x); cBm.y = __builtin_amdgcn_cosf(tBm.y); \
    sC_.x = __builtin_amdgcn_sinf(tC.x);  sC_.y = __builtin_amdgcn_sinf(tC.y);  \
    cC_.x = __builtin_amdgcn_cosf(tC.x);  cC_.y = __builtin_amdgcn_cosf(tC.y);  \
    sP_.x = __builtin_amdgcn_sinf(tP.x);  sP_.y = __builtin_amdgcn_sinf(tP.y);  \
    cP_.x = __builtin_amdgcn_cosf(tP.x);  cP_.y = __builtin_amdgcn_cosf(tP.y);  \
    sM_.x = __builtin_amdgcn_sinf(tM.x);  sM_.y = __builtin_amdgcn_sinf(tM.y);  \
    cM_.x = __builtin_amdgcn_cosf(tM.x);  cM_.y = __builtin_amdgcn_cosf(tM.y); }

#define BUILD_E_P(W0r, W0i, W1r, W1i) do {                                   \
  v2f m00r = pk_mul2(cBp, cC_);                                              \
  v2f m00i = pk_mul2n(cBm, sC_);                                             \
  v2f m01r = pk_mul2n(sBp, cC_);                                             \
  v2f m01i = pk_mul2(sBm, sC_);                                              \
  v2f alr = pk_fma2(m00r, cP_, pk_mul2(m00i, sP_));                          \
  v2f ali = pk_fma2(m00i, cP_, pk_mul2n(m00r, sP_));                         \
  v2f ber = pk_fma2(m01r, cM_, pk_mul2n(m01i, sM_));                         \
  v2f bei = pk_fma2(m01i, cM_, pk_mul2(m01r, sM_));                          \
  W0r = pk_mul2(pk_add2(alr, ber), RSv);                                     \
  W0i = pk_mul2(pk_add2(ali, bei), RSv);                                     \
  W1r = pk_mul2(pk_sub2(alr, ber), RSv);                                     \
  W1i = pk_mul2(pk_sub2(ali, bei), RSv);                                     \
} while (0)

// ---- per-lane angle selects (verified r4), per-image scalar form ----
#define SELM(Ac, Bc, A0, A1, A2, A3, A4)                                     \
  A0 = l3 ? Ac.w : Ac.x;                                                     \
  A1 = l3 ? 0.f  : Ac.y;                                                     \
  A2 = l2 ? Bc.x : (l3 ? 0.f : Ac.z);                                        \
  A3 = l0 ? Ac.w : (l1 ? Bc.x : (l2 ? Bc.y : 0.f));                          \
  A4 = l0 ? Bc.x : (l1 ? Bc.y : (l2 ? Bc.z : 0.f));

#define SELT(Ac, Bc, A0, A1, A2, A3, A4)                                     \
  A0 = l0 ? Ac.x : (l1 ? Ac.y : 0.f);                                        \
  A1 = l0 ? Ac.y : (l1 ? Ac.z : 0.f);                                        \
  A2 = l0 ? Ac.z : (l1 ? Ac.w : 0.f);                                        \
  A3 = l0 ? Ac.w : 0.f;                                                      \
  A4 = l0 ? Bc.x : 0.f;

#define PACKA(X0,X1,X2,X3,X4, Y0,Y1,Y2,Y3,Y4)                                \
  v2f a0, a1, a2, a3, a4;                                                    \
  a0.x = X0; a0.y = Y0; a1.x = X1; a1.y = Y1; a2.x = X2; a2.y = Y2;          \
  a3.x = X3; a3.y = Y3; a4.x = X4; a4.y = Y4;

// ---- 8-lane state (verified r1 mapping): amp n = 8h + 4(q>>1) + 2(q&1) + m
// qubit0 ~ lane^4 (swz4), qubit1 ~ lane^2 (XOR2), qubit2 ~ lane^1 (XOR1),
// qubit3 ~ m (intra-lane). sr[m]/si[m] = (re,im) split, (img0,img1) packed.
// Cross-lane gate stage: s' = u*a + v*p with u=(sxor(w0r,SM), w0i),
// v=(w1r, sxor(w1i,SM))  [r1-verified algebra]
#define GSTAGE(BC, PART, SM) do {                                            \
  v2f uar = sxor2(dpp2<BC>(Wc0r), SM);                                       \
  v2f uai = dpp2<BC>(Wc0i);                                                  \
  v2f ubr = dpp2<BC>(Wc1r);                                                  \
  v2f ubi = sxor2(dpp2<BC>(Wc1i), SM);                                       \
  _Pragma("unroll")                                                          \
  for (int m = 0; m < 2; ++m) {                                              \
    v2f pre = PART(sr[m]), pim = PART(si[m]);                                \
    v2f are = sr[m], aim = si[m];                                            \
    sr[m] = pk_fma2(uar, are, pk_fma2n(uai, aim,                             \
              pk_fma2(ubr, pre, pk_mul2n(ubi, pim))));                       \
    si[m] = pk_fma2(uar, aim, pk_fma2(uai, are,                              \
              pk_fma2(ubr, pim, pk_mul2(ubi, pre))));                        \
  }                                                                          \
} while (0)

// intra-lane stage (qubit3): row0 = w0*a + w1*b ; row1 = conj(w1)*a - conj(w0)*b
#define GSTAGE_INTRA do {                                                    \
  v2f w0r = dpp2<QP_BC3>(Wc0r), w0i = dpp2<QP_BC3>(Wc0i);                    \
  v2f w1r = dpp2<QP_BC3>(Wc1r), w1i = dpp2<QP_BC3>(Wc1i);                    \
  v2f are = sr[0], aim = si[0], bre = sr[1], bim = si[1];                    \
  sr[0] = pk_fma2(w0r, are, pk_fma2n(w0i, aim,                               \
            pk_fma2(w1r, bre, pk_mul2n(w1i, bim))));                         \
  si[0] = pk_fma2(w0r, aim, pk_fma2(w0i, are,                                \
            pk_fma2(w1r, bim, pk_mul2(w1i, bre))));                          \
  sr[1] = pk_fma2(w1r, are, pk_fma2(w1i, aim,                                \
            pk_fma2n(w0r, bre, pk_mul2n(w0i, bim))));                        \
  si[1] = pk_fma2(w1r, aim, pk_fma2n(w1i, are,                               \
            pk_fma2n(w0r, bim, pk_mul2(w0i, bre))));                         \
} while (0)

#define RYSTAGE(PART, RYC) do {                                              \
  _Pragma("unroll")                                                          \
  for (int m = 0; m < 2; ++m) {                                              \
    v2f pre = PART(sr[m]), pim = PART(si[m]);                                \
    sr[m] = pk_fma_rlo(RYC, sr[m], pk_mul_rhi(RYC, pre));                    \
    si[m] = pk_fma_rlo(RYC, si[m], pk_mul_rhi(RYC, pim));                    \
  }                                                                          \
} while (0)

// CRZ diag (per-amp scalar-pair coef CZm=(cz,sz)) + 4 Ry stages (r1-verified)
#define CRZRY do {                                                           \
  { v2f t0 = sr[0];                                                          \
    sr[0] = pk_fma_rlo(CZ0, t0, pk_mul_nrhi(CZ0, si[0]));                    \
    si[0] = pk_fma_rlo(CZ0, si[0], pk_mul_rhi(CZ0, t0)); }                   \
  { v2f t1 = sr[1];                                                          \
    sr[1] = pk_fma_rlo(CZ1, t1, pk_mul_nrhi(CZ1, si[1]));                    \
    si[1] = pk_fma_rlo(CZ1, si[1], pk_mul_rhi(CZ1, t1)); }                   \
  RYSTAGE(SWZ, RYc0);                                                        \
  RYSTAGE(DX2, RYc1);                                                        \
  RYSTAGE(DX1, RYc2);                                                        \
  { v2f r0 = sr[0], i0 = si[0], r1v = sr[1], i1v = si[1];                    \
    sr[0] = pk_fma_rlo(RIc, r0, pk_mul_nrhi(RIc, r1v));                      \
    si[0] = pk_fma_rlo(RIc, i0, pk_mul_nrhi(RIc, i1v));                      \
    sr[1] = pk_fma_rhi(RIc, r0, pk_mul_rlo(RIc, r1v));                       \
    si[1] = pk_fma_rhi(RIc, i0, pk_mul_rlo(RIc, i1v)); }                     \
} while (0)

#define READOUT do {                                                         \
  v2f pr0 = pk_fma2(si[0], si[0], pk_mul2(sr[0], sr[0]));                    \
  v2f pr1 = pk_fma2(si[1], si[1], pk_mul2(sr[1], sr[1]));                    \
  v2f t_  = pk_add2(pr0, pr1);                                               \
  np0 = sxor2(t_, smH); np1 = sxor2(t_, sm2);                                \
  np2 = sxor2(t_, sm1); np3 = pk_sub2(pr0, pr1);                             \
} while (0)

#define APPLY_ZP do {                                                        \
  GSTAGE(QP_BC0, SWZ, smH);                                                  \
  GSTAGE(QP_BC1, DX2, sm2);                                                  \
  GSTAGE(QP_BC2, DX1, sm1);                                                  \
  GSTAGE_INTRA;                                                              \
  CRZRY;                                                                     \
  READOUT;                                                                   \
} while (0)

// ---- deferred butterfly + fc1 fold (r1-verified exchange), packed imgs ----
#define BF_LOAD                                                              \
  const float* wp = swl + pdWin * 4;                                         \
  v2f wv0 = *(const v2f*)(wp);                                               \
  v2f wv1 = *(const v2f*)(wp + 784);                                         \
  v2f wv2 = *(const v2f*)(wp + 1568);                                        \
  v2f wv3 = *(const v2f*)(wp + 2352);                                        \
  v2f wv4 = *(const v2f*)(wp + 3136);

#define BF_BFLY                                                              \
  v2f o0 = pd0, o1 = pd1, o2 = pd2, o3 = pd3;                                \
  o0 = pk_add2(o0, DX1(o0)); o0 = pk_add2(o0, DX2(o0));                      \
  o1 = pk_add2(o1, DX1(o1)); o1 = pk_add2(o1, DX2(o1));                      \
  o2 = pk_add2(o2, DX1(o2)); o2 = pk_add2(o2, DX2(o2));                      \
  o3 = pk_add2(o3, DX1(o3)); o3 = pk_add2(o3, DX2(o3));                      \
  v2f uA = hsel ? o0 : o2, uB = hsel ? o1 : o3;                              \
  v2f fa = pk_add2(hsel ? o2 : o0, swz4v(uA));                               \
  v2f fb = pk_add2(hsel ? o3 : o1, swz4v(uB));

#define BF_FMA                                                               \
  h1v[0] = pk_fma_rlo(wv0, fa, pk_fma_rhi(wv0, fb, h1v[0]));                 \
  h1v[1] = pk_fma_rlo(wv1, fa, pk_fma_rhi(wv1, fb, h1v[1]));                 \
  h1v[2] = pk_fma_rlo(wv2, fa, pk_fma_rhi(wv2, fb, h1v[2]));                 \
  h1v[3] = pk_fma_rlo(wv3, fa, pk_fma_rhi(wv3, fb, h1v[3]));                 \
  h1v[4] = pk_fma_rlo(wv4, fa, pk_fma_rhi(wv4, fb, h1v[4]));

#define BF_FOLDP do { BF_LOAD; BF_BFLY; BF_FMA; } while (0)

#define SHIFT_PEND(WIN)  pd0 = np0; pd1 = np1; pd2 = np2; pd3 = np3; pdWin = (WIN);
#define ROTATE_W  Wc0r = Wn0r; Wc0i = Wn0i; Wc1r = Wn1r; Wc1i = Wn1i;

__global__ void __launch_bounds__(256)
quanv_kernel(const float* __restrict__ x,
             const float* __restrict__ crz_t,
             const float* __restrict__ ry_t,
             const float* __restrict__ fc1_w,
             const float* __restrict__ fc1_b,
             const float* __restrict__ fc2_w,
             const float* __restrict__ fc2_b,
             float* __restrict__ out, int B)
{
  __shared__ float sw[20 * 784];
  const int tid = threadIdx.x;
  for (int i = tid; i < (20 * 784) / 4; i += 256)
    ((float4*)sw)[i] = ((const float4*)fc1_w)[i];
  __syncthreads();

  const int l8   = tid & 7;        // lane within 8-lane group
  const int q    = l8 & 3;         // quad lane = gate-builder qubit id
  const int hsel = l8 >> 2;        // qubit0 bit (cross-quad half)
  const int b    = (blockIdx.x * 256 + tid) >> 3;  // image PAIR id
  if (2 * b >= B) return;
  const float* img0 = x + (size_t)(2 * b) * 784;
  const float* img1 = img0 + 784;
  const bool l0 = (q == 0), l1 = (q == 1), l2 = (q == 2), l3 = (q == 3);

  // per-lane load offsets (r4-verified direct-select scheme)
  const int offA = l3 ? 84 : q * 29;
  const int offB = (q >= 2) ? 84 : (q + 1) * 28;

  // ---- uniform constants ----
  const float theta = crz_t[0];
  const float ryt   = ry_t[0];
  float cry, sry;
  hsc(ryt, &sry, &cry);
  const int SBIT = (int)0x80000000;
  const int smH = hsel    ? SBIT : 0;
  const int sm2 = (q & 2) ? SBIT : 0;
  const int sm1 = (q & 1) ? SBIT : 0;
  const float sgn0 = hsel    ? sry : -sry;
  const float sgn1 = (q & 2) ? sry : -sry;
  const float sgn2 = (q & 1) ? sry : -sry;

  v2f RYc0, RYc1, RYc2, RIc, KK, RSv;
  RYc0.x = cry; RYc0.y = sgn0;
  RYc1.x = cry; RYc1.y = sgn1;
  RYc2.x = cry; RYc2.y = sgn2;
  RIc.x  = cry; RIc.y  = sry;
  KK.x = KHALF; KK.y = KHALF;
  RSv.x = RS2f; RSv.y = RS2f;

  // CRZ diag signs per amp (r1-verified formulas)
  const int B1b = (q >> 1) & 1, B2b = q & 1;
  const int gb = hsel * (2 * B1b - 1) + B1b * (2 * B2b - 1);
  const float g0f = (float)(gb - B2b);
  const float g1f = (float)(gb + B2b + 2 * hsel - 1);
  v2f CZ0, CZ1;
  { float sz, cz;
    hsc(theta * g0f, &sz, &cz); CZ0.x = cz; CZ0.y = sz;
    hsc(theta * g1f, &sz, &cz); CZ1.x = cz; CZ1.y = sz; }

  // state: 2 amps/lane, re/im split, (img0,img1) packed
  v2f sr[2], si[2];
  sr[0] = (v2f)0.f; sr[1] = (v2f)0.f; si[0] = (v2f)0.f; si[1] = (v2f)0.f;
  if (l8 == 0) { sr[0].x = 1.f; sr[0].y = 1.f; }

  v2f h1v[5];
#pragma unroll
  for (int j = 0; j < 5; ++j) h1v[j] = (v2f)0.f;
  const float* swl = sw + 5 * q * 784 + 2 * hsel;   // r1-verified

  v2f Wc0r, Wc0i, Wc1r, Wc1i, Wn0r, Wn0i, Wn1r, Wn1i;
  v2f np0, np1, np2, np3;
  v2f pd0 = (v2f)0.f, pd1 = (v2f)0.f, pd2 = (v2f)0.f, pd3 = (v2f)0.f;
  int pdWin = 0;

  // ================= main rows: wi = 0..12 =================
#pragma unroll 1
  for (int wi = 0; wi < 13; ++wi) {
    const float* rp0 = img0 + (2 * wi) * 28;
    const float* rp1 = img1 + (2 * wi) * 28;
    const float* pA0 = rp0 + offA;
    const float* pB0 = rp0 + offB;
    const float* pA1 = rp1 + offA;
    const float* pB1 = rp1 + offB;

    // peel wj = 0
    {
      v4f Ac0 = loadu4(pA0), Bc0 = loadu4(pB0);
      v4f Ac1 = loadu4(pA1), Bc1 = loadu4(pB1);
      float x0,x1,x2,x3,x4, y0,y1,y2,y3,y4;
      SELM(Ac0, Bc0, x0, x1, x2, x3, x4);
      SELM(Ac1, Bc1, y0, y1, y2, y3, y4);
      PACKA(x0,x1,x2,x3,x4, y0,y1,y2,y3,y4);
      BUILD_T_P;
      BUILD_E_P(Wc0r, Wc0i, Wc1r, Wc1i);
    }

    v4f An0 = loadu4(pA0 + 2), Bn0 = loadu4(pB0 + 2);
    v4f An1 = loadu4(pA1 + 2), Bn1 = loadu4(pB1 + 2);

#pragma unroll 2
    for (int wj = 1; wj <= 12; ++wj) {
      BF_LOAD;
      v4f Ac0 = An0, Bc0 = Bn0, Ac1 = An1, Bc1 = Bn1;
      const int jn = (wj < 12) ? 2 * (wj + 1) : 24;
      An0 = loadu4(pA0 + jn); Bn0 = loadu4(pB0 + jn);
      An1 = loadu4(pA1 + jn); Bn1 = loadu4(pB1 + jn);
      float x0,x1,x2,x3,x4, y0,y1,y2,y3,y4;
      SELM(Ac0, Bc0, x0, x1, x2, x3, x4);
      SELM(Ac1, Bc1, y0, y1, y2, y3, y4);
      PACKA(x0,x1,x2,x3,x4, y0,y1,y2,y3,y4);
      BUILD_T_P;
      BF_BFLY;
      GSTAGE(QP_BC0, SWZ, smH);
      GSTAGE(QP_BC1, DX2, sm2);
      BUILD_E_P(Wn0r, Wn0i, Wn1r, Wn1i);
      GSTAGE(QP_BC2, DX1, sm1);
      GSTAGE_INTRA;
      BF_FMA;
      CRZRY;
      READOUT;
      SHIFT_PEND(wi * 14 + wj - 1);
      ROTATE_W;
    }

    // peel wj = 13: w=2 window (cols 26,27)
    {
      v2f C00 = *(const v2f*)(rp0 + (l1 ? 56 : 0)  + 26);
      v2f C01 = *(const v2f*)(rp0 + (l1 ? 84 : 28) + 26);
      v2f C02 = *(const v2f*)(rp0 + (l1 ? 84 : 56) + 26);
      v2f C10 = *(const v2f*)(rp1 + (l1 ? 56 : 0)  + 26);
      v2f C11 = *(const v2f*)(rp1 + (l1 ? 84 : 28) + 26);
      v2f C12 = *(const v2f*)(rp1 + (l1 ? 84 : 56) + 26);
      float x0 = l0 ? C00.x : (l1 ? C00.y : 0.f);
      float x1 = l0 ? C00.y : (l1 ? C01.x : 0.f);
      float x2 = l0 ? C01.x : (l1 ? C01.y : 0.f);
      float x3 = l0 ? C01.y : 0.f;
      float x4 = l0 ? C02.x : 0.f;
      float y0 = l0 ? C10.x : (l1 ? C10.y : 0.f);
      float y1 = l0 ? C10.y : (l1 ? C11.x : 0.f);
      float y2 = l0 ? C11.x : (l1 ? C11.y : 0.f);
      float y3 = l0 ? C11.y : 0.f;
      float y4 = l0 ? C12.x : 0.f;
      PACKA(x0,x1,x2,x3,x4, y0,y1,y2,y3,y4);
      BUILD_T_P;
      BUILD_E_P(Wn0r, Wn0i, Wn1r, Wn1i);
    }
    APPLY_ZP;                                    // window 12
    BF_FOLDP;                                    // window 11
    SHIFT_PEND(wi * 14 + 12);
    ROTATE_W;
    APPLY_ZP;                                    // window 13
    BF_FOLDP;                                    // window 12
    SHIFT_PEND(wi * 14 + 13);
  }

  // ================= tail row: wi = 13 (h = 2) =================
  {
    const float* pA0 = img0 + 728 + (l1 ? 28 : 0);
    const float* pB0 = img0 + 756;
    const float* pA1 = img1 + 728 + (l1 ? 28 : 0);
    const float* pB1 = img1 + 756;

    {
      v4f Ac0 = loadu4(pA0), Bc0 = loadu4(pB0);
      v4f Ac1 = loadu4(pA1), Bc1 = loadu4(pB1);
      float x0,x1,x2,x3,x4, y0,y1,y2,y3,y4;
      SELT(Ac0, Bc0, x0, x1, x2, x3, x4);
      SELT(Ac1, Bc1, y0, y1, y2, y3, y4);
      PACKA(x0,x1,x2,x3,x4, y0,y1,y2,y3,y4);
      BUILD_T_P;
      BUILD_E_P(Wc0r, Wc0i, Wc1r, Wc1i);
    }

    v4f An0 = loadu4(pA0 + 2), Bn0 = loadu4(pB0 + 2);
    v4f An1 = loadu4(pA1 + 2), Bn1 = loadu4(pB1 + 2);

#pragma unroll 2
    for (int wj = 1; wj <= 12; ++wj) {
      BF_LOAD;
      v4f Ac0 = An0, Bc0 = Bn0, Ac1 = An1, Bc1 = Bn1;
      const int jn = (wj < 12) ? 2 * (wj + 1) : 24;
      An0 = loadu4(pA0 + jn); Bn0 = loadu4(pB0 + jn);
      An1 = loadu4(pA1 + jn); Bn1 = loadu4(pB1 + jn);
      float x0,x1,x2,x3,x4, y0,y1,y2,y3,y4;
      SELT(Ac0, Bc0, x0, x1, x2, x3, x4);
      SELT(Ac1, Bc1, y0, y1, y2, y3, y4);
      PACKA(x0,x1,x2,x3,x4, y0,y1,y2,y3,y4);
      BUILD_T_P;
      BF_BFLY;
      GSTAGE(QP_BC0, SWZ, smH);
      GSTAGE(QP_BC1, DX2, sm2);
      BUILD_E_P(Wn0r, Wn0i, Wn1r, Wn1i);
      GSTAGE(QP_BC2, DX1, sm1);
      GSTAGE_INTRA;
      BF_FMA;
      CRZRY;
      READOUT;
      SHIFT_PEND(182 + wj - 1);
      ROTATE_W;
    }

    // peel wj = 13: 2x2 window, l0 only
    {
      v2f D00 = *(const v2f*)(img0 + 26 * 28 + 26);
      v2f D01 = *(const v2f*)(img0 + 27 * 28 + 26);
      v2f D10 = *(const v2f*)(img1 + 26 * 28 + 26);
      v2f D11 = *(const v2f*)(img1 + 27 * 28 + 26);
      float x0 = l0 ? D00.x : 0.f, x1 = l0 ? D00.y : 0.f;
      float x2 = l0 ? D01.x : 0.f, x3 = l0 ? D01.y : 0.f, x4 = 0.f;
      float y0 = l0 ? D10.x : 0.f, y1 = l0 ? D10.y : 0.f;
      float y2 = l0 ? D11.x : 0.f, y3 = l0 ? D11.y : 0.f, y4 = 0.f;
      PACKA(x0,x1,x2,x3,x4, y0,y1,y2,y3,y4);
      BUILD_T_P;
      BUILD_E_P(Wn0r, Wn0i, Wn1r, Wn1i);
    }
    APPLY_ZP;                                    // window 194
    BF_FOLDP;                                    // window 193
    SHIFT_PEND(182 + 12);
    ROTATE_W;
    APPLY_ZP;                                    // window 195
    BF_FOLDP;                                    // window 194
    SHIFT_PEND(182 + 13);
  }

  // drain: fold window 195
  BF_FOLDP;

  // combine half-groups' fc1 partials (r1-verified)
#pragma unroll
  for (int j = 0; j < 5; ++j) h1v[j] = pk_add2(h1v[j], swz4v(h1v[j]));

  // ---- epilogue (cold): bias + leaky relu + fc2, per image ----
  float pa0 = 0.f, pb0 = 0.f, pa1 = 0.f, pb1 = 0.f;
#pragma unroll
  for (int j = 0; j < 5; ++j) {
    const int r = 5 * q + j;
    const float bb = fc1_b[r];
    const float w2a = fc2_w[r], w2b = fc2_w[20 + r];
    float v0 = h1v[j].x + bb; v0 = (v0 > 0.f) ? v0 : 0.1f * v0;
    float v1 = h1v[j].y + bb; v1 = (v1 > 0.f) ? v1 : 0.1f * v1;
    pa0 = fmaf(w2a, v0, pa0); pb0 = fmaf(w2b, v0, pb0);
    pa1 = fmaf(w2a, v1, pa1); pb1 = fmaf(w2b, v1, pb1);
  }
  pa0 += dppf<QP_XOR1>(pa0); pa0 += dppf<QP_XOR2>(pa0);
  pb0 += dppf<QP_XOR1>(pb0); pb0 += dppf<QP_XOR2>(pb0);
  pa1 += dppf<QP_XOR1>(pa1); pa1 += dppf<QP_XOR2>(pa1);
  pb1 += dppf<QP_XOR1>(pb1); pb1 += dppf<QP_XOR2>(pb1);
  if (l8 == 0) {
    float4 res;
    res.x = pa0 + fc2_b[0]; res.y = pb0 + fc2_b[1];
    res.z = pa1 + fc2_b[0]; res.w = pb1 + fc2_b[1];
    *(float4*)(out + (size_t)4 * b) = res;
  }
}

extern "C" void kernel_launch(void* const* d_in, const int* in_sizes, int n_in,
                              void* d_out, int out_size, void* d_ws, size_t ws_size,
                              hipStream_t stream) {
  const float* x      = (const float*)d_in[0];
  const float* crz_t  = (const float*)d_in[1];
  const float* ry_t   = (const float*)d_in[2];
  const float* fc1_w  = (const float*)d_in[3];
  const float* fc1_b  = (const float*)d_in[4];
  const float* fc2_w  = (const float*)d_in[5];
  const float* fc2_b  = (const float*)d_in[6];
  float* out = (float*)d_out;
  const int B = in_sizes[0] / 784;
  const int grid = (B * 4 + 255) / 256;   // 8 lanes per 2 images = 4*B lanes
  quanv_kernel<<<grid, 256, 0, stream>>>(x, crz_t, ry_t, fc1_w, fc1_b,
                                         fc2_w, fc2_b, out, B);
}

// Round 9
// 212.843 us; speedup vs baseline: 1.2195x; 1.2195x over previous
//
#include <hip/hip_runtime.h>

#define RS2f 0.70710678118654752f

// DPP quad_perm encodings: sel0 | sel1<<2 | sel2<<4 | sel3<<6
#define QP_XOR1 0xB1   // [1,0,3,2]
#define QP_XOR2 0x4E   // [2,3,0,1]
#define QP_BC0  0x00
#define QP_BC1  0x55
#define QP_BC2  0xAA
#define QP_BC3  0xFF

typedef float v2f __attribute__((ext_vector_type(2)));
typedef float v4f __attribute__((ext_vector_type(4)));
typedef v4f v4fu __attribute__((aligned(4)));   // 4B-aligned vector load

template<int CTRL> __device__ __forceinline__ float dppf(float x) {
  return __int_as_float(__builtin_amdgcn_update_dpp(
      0, __float_as_int(x), CTRL, 0xF, 0xF, true));
}
template<int CTRL> __device__ __forceinline__ v2f dpp2(v2f v) {
  v2f r; r.x = dppf<CTRL>(v.x); r.y = dppf<CTRL>(v.y); return r;
}

__device__ __forceinline__ float sxor(float x, int sm) {
  return __int_as_float(__float_as_int(x) ^ sm);
}
__device__ __forceinline__ v2f vlo(v4f v) { return __builtin_shufflevector(v, v, 0, 1); }
__device__ __forceinline__ v2f vhi(v4f v) { return __builtin_shufflevector(v, v, 2, 3); }
__device__ __forceinline__ v4f loadu4(const float* p) { return *(const v4fu*)p; }

// ---- packed-fp32 helpers: complex / packed arithmetic in single VOP3P ops --
// perp(x) = (-x.y, x.x) = i*x ; perc(x) = (x.y, -x.x) = -i*x

// plain packed: d = a*b + c
__device__ __forceinline__ v2f pk_fma2(v2f a, v2f b, v2f c) {
  v2f d;
  asm("v_pk_fma_f32 %0, %1, %2, %3 op_sel:[0,0,0] op_sel_hi:[1,1,1]"
      : "=v"(d) : "v"(a), "v"(b), "v"(c));
  return d;
}
// plain packed: d = a*b
__device__ __forceinline__ v2f pk_mul2(v2f a, v2f b) {
  v2f d;
  asm("v_pk_mul_f32 %0, %1, %2 op_sel:[0,0] op_sel_hi:[1,1]"
      : "=v"(d) : "v"(a), "v"(b));
  return d;
}
// plain packed: d = a + b
__device__ __forceinline__ v2f pk_add2(v2f a, v2f b) {
  v2f d;
  asm("v_pk_add_f32 %0, %1, %2 op_sel:[0,0] op_sel_hi:[1,1]"
      : "=v"(d) : "v"(a), "v"(b));
  return d;
}
// d = c.lo * x + acc
__device__ __forceinline__ v2f pk_fma_rlo(v2f c, v2f x, v2f acc) {
  v2f d;
  asm("v_pk_fma_f32 %0, %1, %2, %3 op_sel:[0,0,0] op_sel_hi:[0,1,1]"
      : "=v"(d) : "v"(c), "v"(x), "v"(acc));
  return d;
}
// d = -c.lo * x + acc
__device__ __forceinline__ v2f pk_fma_nrlo(v2f c, v2f x, v2f acc) {
  v2f d;
  asm("v_pk_fma_f32 %0, %1, %2, %3 op_sel:[0,0,0] op_sel_hi:[0,1,1] neg_lo:[1,0,0] neg_hi:[1,0,0]"
      : "=v"(d) : "v"(c), "v"(x), "v"(acc));
  return d;
}
// d = c.hi * x + acc
__device__ __forceinline__ v2f pk_fma_rhi(v2f c, v2f x, v2f acc) {
  v2f d;
  asm("v_pk_fma_f32 %0, %1, %2, %3 op_sel:[1,0,0] op_sel_hi:[1,1,1]"
      : "=v"(d) : "v"(c), "v"(x), "v"(acc));
  return d;
}
// d = -c.hi * x + acc
__device__ __forceinline__ v2f pk_fma_nrhi(v2f c, v2f x, v2f acc) {
  v2f d;
  asm("v_pk_fma_f32 %0, %1, %2, %3 op_sel:[1,0,0] op_sel_hi:[1,1,1] neg_lo:[1,0,0] neg_hi:[1,0,0]"
      : "=v"(d) : "v"(c), "v"(x), "v"(acc));
  return d;
}
// d = c.hi * perp(x) + acc
__device__ __forceinline__ v2f pk_fma_rhip(v2f c, v2f x, v2f acc) {
  v2f d;
  asm("v_pk_fma_f32 %0, %1, %2, %3 op_sel:[1,1,0] op_sel_hi:[1,0,1] neg_lo:[0,1,0]"
      : "=v"(d) : "v"(c), "v"(x), "v"(acc));
  return d;
}
// d = c.hi * perc(x) + acc
__device__ __forceinline__ v2f pk_fma_rhic(v2f c, v2f x, v2f acc) {
  v2f d;
  asm("v_pk_fma_f32 %0, %1, %2, %3 op_sel:[1,1,0] op_sel_hi:[1,0,1] neg_hi:[0,1,0]"
      : "=v"(d) : "v"(c), "v"(x), "v"(acc));
  return d;
}
// d = c.hi * perp(x)
__device__ __forceinline__ v2f pk_mul_rhip(v2f c, v2f x) {
  v2f d;
  asm("v_pk_mul_f32 %0, %1, %2 op_sel:[1,1] op_sel_hi:[1,0] neg_lo:[0,1]"
      : "=v"(d) : "v"(c), "v"(x));
  return d;
}
// d = c.hi * perc(x)
__device__ __forceinline__ v2f pk_mul_rhic(v2f c, v2f x) {
  v2f d;
  asm("v_pk_mul_f32 %0, %1, %2 op_sel:[1,1] op_sel_hi:[1,0] neg_hi:[0,1]"
      : "=v"(d) : "v"(c), "v"(x));
  return d;
}
// d = c.hi * x
__device__ __forceinline__ v2f pk_mul_rhi(v2f c, v2f x) {
  v2f d;
  asm("v_pk_mul_f32 %0, %1, %2 op_sel:[1,0] op_sel_hi:[1,1]"
      : "=v"(d) : "v"(c), "v"(x));
  return d;
}
// d = -c.hi * x
__device__ __forceinline__ v2f pk_mul_nrhi(v2f c, v2f x) {
  v2f d;
  asm("v_pk_mul_f32 %0, %1, %2 op_sel:[1,0] op_sel_hi:[1,1] neg_lo:[1,0] neg_hi:[1,0]"
      : "=v"(d) : "v"(c), "v"(x));
  return d;
}
// d = c.lo * x
__device__ __forceinline__ v2f pk_mul_rlo(v2f c, v2f x) {
  v2f d;
  asm("v_pk_mul_f32 %0, %1, %2 op_sel:[0,0] op_sel_hi:[0,1]"
      : "=v"(d) : "v"(c), "v"(x));
  return d;
}

// native half-angle sincos: s = sin(x/2), c = cos(x/2)
__device__ __forceinline__ void hsc(float x, float* s, float* c) {
  float t = x * 0.07957747154594767f;   // 0.5 / (2*pi), input in revolutions
  *s = __builtin_amdgcn_sinf(t);
  *c = __builtin_amdgcn_cosf(t);
}

// Closed-form row0 of U = RZ(a4)RY(a3)RZ(a2)RY(a1)RZ(a0)·H  (verified r8).
__device__ __forceinline__ void build_gate(float a0, float a1, float a2, float a3, float a4,
                                           v2f &WA, v2f &WB) {
  float sBp, cBp, sBm, cBm, sC, cC, sP, cP, sM, cM;
  hsc(a1 + a3, &sBp, &cBp);
  hsc(a1 - a3, &sBm, &cBm);
  hsc(a2,      &sC,  &cC);
  hsc(a0 + a4, &sP,  &cP);
  hsc(a0 - a4, &sM,  &cM);
  float m00r =  cBp * cC, m00i = -cBm * sC;
  float m01r = -sBp * cC, m01i =  sBm * sC;
  float alr = fmaf(m00r, cP,  m00i * sP);
  float ali = fmaf(m00i, cP, -m00r * sP);
  float ber = fmaf(m01r, cM, -m01i * sM);
  float bei = fmaf(m01i, cM,  m01r * sM);
  WA.x = RS2f * (alr + ber); WA.y = RS2f * (ali + bei);
  WB.x = RS2f * (alr - ber); WB.y = RS2f * (ali - bei);
}

// ---- per-lane direct angle selects (verified r4) ----
#define SEL_MAIN                                                             \
  a0 = l3 ? Ac.w : Ac.x;                                                     \
  a1 = l3 ? 0.f  : Ac.y;                                                     \
  a2 = l2 ? Bc.x : (l3 ? 0.f : Ac.z);                                        \
  a3 = l0 ? Ac.w : (l1 ? Bc.x : (l2 ? Bc.y : 0.f));                          \
  a4 = l0 ? Bc.x : (l1 ? Bc.y : (l2 ? Bc.z : 0.f));

#define SEL_TAIL                                                             \
  a0 = l0 ? Ac.x : (l1 ? Ac.y : 0.f);                                        \
  a1 = l0 ? Ac.y : (l1 ? Ac.z : 0.f);                                        \
  a2 = l0 ? Ac.z : (l1 ? Ac.w : 0.f);                                        \
  a3 = l0 ? Ac.w : 0.f;                                                      \
  a4 = l0 ? Bc.x : 0.f;

// Apply gate (WcA/WcB packed pairs) + CRZ + Ry + Z expectations.
// Math identical to r5-verified APPLY_Z; the 4-deep FMA chains in the four
// gate stages are split into two parallel 2-chains + pk_add (shorter tail).
#define APPLY_Z do {                                                         \
  { v2f UA = dpp2<QP_BC0>(WcA), UB = dpp2<QP_BC0>(WcB);                      \
    UA.x = sxor(UA.x, sm0); UB.y = sxor(UB.y, sm0);                          \
    _Pragma("unroll")                                                        \
    for (int k = 0; k < 4; ++k) {                                            \
      v2f p = dpp2<QP_XOR2>(s[k]);                                           \
      v2f a = s[k];                                                          \
      v2f tA = pk_fma_rlo(UA, a, pk_mul_rhip(UA, a));                        \
      v2f tB = pk_fma_rlo(UB, p, pk_mul_rhip(UB, p));                        \
      s[k] = pk_add2(tA, tB);                                                \
    } }                                                                      \
  { v2f UA = dpp2<QP_BC1>(WcA), UB = dpp2<QP_BC1>(WcB);                      \
    UA.x = sxor(UA.x, sm1); UB.y = sxor(UB.y, sm1);                          \
    _Pragma("unroll")                                                        \
    for (int k = 0; k < 4; ++k) {                                            \
      v2f p = dpp2<QP_XOR1>(s[k]);                                           \
      v2f a = s[k];                                                          \
      v2f tA = pk_fma_rlo(UA, a, pk_mul_rhip(UA, a));                        \
      v2f tB = pk_fma_rlo(UB, p, pk_mul_rhip(UB, p));                        \
      s[k] = pk_add2(tA, tB);                                                \
    } }                                                                      \
  { v2f W0 = dpp2<QP_BC2>(WcA), W1 = dpp2<QP_BC2>(WcB);                      \
    _Pragma("unroll")                                                        \
    for (int k = 0; k < 2; ++k) {                                            \
      v2f lo = s[k], hi = s[k+2];                                            \
      v2f tA = pk_fma_rlo(W0, lo, pk_mul_rhip(W0, lo));                      \
      v2f tB = pk_fma_rlo(W1, hi, pk_mul_rhip(W1, hi));                      \
      v2f tC = pk_fma_rlo(W1, lo, pk_mul_rhic(W1, lo));                      \
      v2f tD = pk_fma_nrlo(W0, hi, pk_mul_rhip(W0, hi));                     \
      s[k]   = pk_add2(tA, tB);                                              \
      s[k+2] = pk_add2(tC, tD);                                              \
    } }                                                                      \
  { v2f W0 = dpp2<QP_BC3>(WcA), W1 = dpp2<QP_BC3>(WcB);                      \
    _Pragma("unroll")                                                        \
    for (int k = 0; k < 4; k += 2) {                                         \
      v2f lo = s[k], hi = s[k+1];                                            \
      v2f tA = pk_fma_rlo(W0, lo, pk_mul_rhip(W0, lo));                      \
      v2f tB = pk_fma_rlo(W1, hi, pk_mul_rhip(W1, hi));                      \
      v2f tC = pk_fma_rlo(W1, lo, pk_mul_rhic(W1, lo));                      \
      v2f tD = pk_fma_nrlo(W0, hi, pk_mul_rhip(W0, hi));                     \
      s[k]   = pk_add2(tA, tB);                                              \
      s[k+1] = pk_add2(tC, tD);                                              \
    } }                                                                      \
  _Pragma("unroll")                                                          \
  for (int k = 0; k < 4; ++k)                                                \
    s[k] = pk_fma_rlo(czv[k], s[k], pk_mul_rhip(czv[k], s[k]));              \
  _Pragma("unroll")                                                          \
  for (int k = 0; k < 4; ++k) {                                              \
    v2f p = dpp2<QP_XOR2>(s[k]);                                             \
    s[k] = pk_fma_rlo(RY0, s[k], pk_mul_rhi(RY0, p));                        \
  }                                                                          \
  _Pragma("unroll")                                                          \
  for (int k = 0; k < 4; ++k) {                                              \
    v2f p = dpp2<QP_XOR1>(s[k]);                                             \
    s[k] = pk_fma_rlo(RY1, s[k], pk_mul_rhi(RY1, p));                        \
  }                                                                          \
  { /* merged intra-lane Ry⊗Ry (r5-verified) */                              \
    v2f t0 = s[0], t1 = s[1], t2 = s[2], t3 = s[3];                          \
    s[0] = pk_fma_rlo(C2CS, t0, pk_fma_nrhi(C2CS, t1,                        \
             pk_fma_nrhi(C2CS, t2, pk_mul_rlo(S2CS, t3))));                  \
    s[1] = pk_fma_rhi(C2CS, t0, pk_fma_rlo(C2CS, t1,                         \
             pk_fma_nrlo(S2CS, t2, pk_mul_nrhi(C2CS, t3))));                 \
    s[2] = pk_fma_rhi(C2CS, t0, pk_fma_nrlo(S2CS, t1,                        \
             pk_fma_rlo(C2CS, t2, pk_mul_nrhi(C2CS, t3))));                  \
    s[3] = pk_fma_rlo(S2CS, t0, pk_fma_rhi(C2CS, t1,                         \
             pk_fma_rhi(C2CS, t2, pk_mul_rlo(C2CS, t3))));                   \
  }                                                                          \
  { v2f q0 = pk_mul2(s[0], s[0]), q1 = pk_mul2(s[1], s[1]);                  \
    v2f q2 = pk_mul2(s[2], s[2]), q3 = pk_mul2(s[3], s[3]);                  \
    float p0 = q0.x + q0.y, p1 = q1.x + q1.y;                                \
    float p2 = q2.x + q2.y, p3 = q3.x + q3.y;                                \
    float s01 = p0 + p1, s23 = p2 + p3;                                      \
    float t_  = s01 + s23;                                                   \
    npA.x = sxor(t_, sm0);                                                   \
    npA.y = sxor(t_, sm1);                                                   \
    npB.x = s01 - s23;                                                       \
    npB.y = (p0 - p1) + (p2 - p3);                                           \
  }                                                                          \
} while (0)

// LDS weight reads for the PENDING window — issued early (top of body).
#define BF_LOAD                                                              \
  const float* wp = swl + pdWin * 4;                                         \
  v4f wv0 = *(const v4f*)(wp);                                               \
  v4f wv1 = *(const v4f*)(wp + 784);                                         \
  v4f wv2 = *(const v4f*)(wp + 1568);                                        \
  v4f wv3 = *(const v4f*)(wp + 2352);                                        \
  v4f wv4 = *(const v4f*)(wp + 3136);

// Packed butterfly + packed fc1 fold — all through explicit pk asm.
#define BF_USE do {                                                          \
  v2f oA = pdA, oB = pdB;                                                    \
  oA = pk_add2(oA, dpp2<QP_XOR1>(oA)); oA = pk_add2(oA, dpp2<QP_XOR2>(oA));  \
  oB = pk_add2(oB, dpp2<QP_XOR1>(oB)); oB = pk_add2(oB, dpp2<QP_XOR2>(oB));  \
  h1v[0] = pk_fma2(vlo(wv0), oA, pk_fma2(vhi(wv0), oB, h1v[0]));             \
  h1v[1] = pk_fma2(vlo(wv1), oA, pk_fma2(vhi(wv1), oB, h1v[1]));             \
  h1v[2] = pk_fma2(vlo(wv2), oA, pk_fma2(vhi(wv2), oB, h1v[2]));             \
  h1v[3] = pk_fma2(vlo(wv3), oA, pk_fma2(vhi(wv3), oB, h1v[3]));             \
  h1v[4] = pk_fma2(vlo(wv4), oA, pk_fma2(vhi(wv4), oB, h1v[4]));             \
} while (0)

#define BF_FOLD do { BF_LOAD; BF_USE; } while (0)

#define SHIFT_PEND(WIN)  pdA = npA; pdB = npB; pdWin = (WIN);
#define ROTATE_W  WcA = WnA; WcB = WnB;

__global__ void __launch_bounds__(256)
quanv_kernel(const float* __restrict__ x,
             const float* __restrict__ crz_t,
             const float* __restrict__ ry_t,
             const float* __restrict__ fc1_w,
             const float* __restrict__ fc1_b,
             const float* __restrict__ fc2_w,
             const float* __restrict__ fc2_b,
             float* __restrict__ out, int B)
{
  __shared__ float sw[20 * 784];
  const int tid = threadIdx.x;
  for (int i = tid; i < (20 * 784) / 4; i += 256)
    ((float4*)sw)[i] = ((const float4*)fc1_w)[i];
  __syncthreads();

  const int l = tid & 3;                       // lane within 4-lane group
  const int b = (blockIdx.x * 256 + tid) >> 2; // element id
  if (b >= B) return;
  const float* img = x + (size_t)b * 784;
  const bool l0 = (l == 0), l1 = (l == 1), l2 = (l == 2), l3 = (l == 3);

  // per-lane load offsets (floats) for the direct-select scheme
  const int offA = l3 ? 84 : l * 29;                 // row i+l, col +l (l3: row i+3, col +0)
  const int offB = (l >= 2) ? 84 : (l + 1) * 28;     // row i+min(l+1,3), col +0

  // ---- uniform scalar-derived constants ----
  const float theta = crz_t[0];
  const float ryt   = ry_t[0];
  float cry, sry;
  hsc(ryt, &sry, &cry);
  const float sgn0 = (l & 2) ? sry : -sry;
  const float sgn1 = (l & 1) ? sry : -sry;
  const int sm0 = (l & 2) ? (int)0x80000000 : 0;
  const int sm1 = (l & 1) ? (int)0x80000000 : 0;

  v2f RY0, RY1, C2CS, S2CS;
  RY0.x = cry; RY0.y = sgn0;
  RY1.x = cry; RY1.y = sgn1;
  C2CS.x = cry * cry; C2CS.y = cry * sry;   // (c^2, c*s)
  S2CS.x = sry * sry; S2CS.y = cry * sry;   // (s^2, c*s)

  float g0,g1,g2,g3;
  if      (l == 0) { g0= 0.f; g1=-1.f; g2=-1.f; g3=0.f; }
  else if (l == 1) { g0=-1.f; g1=-2.f; g2= 0.f; g3=1.f; }
  else if (l == 2) { g0=-1.f; g1= 0.f; g2=-2.f; g3=1.f; }
  else             { g0= 0.f; g1= 1.f; g2= 1.f; g3=4.f; }
  v2f czv[4];
  { float sz, cz;
    hsc(theta*g0, &sz, &cz); czv[0].x = cz; czv[0].y = sz;
    hsc(theta*g1, &sz, &cz); czv[1].x = cz; czv[1].y = sz;
    hsc(theta*g2, &sz, &cz); czv[2].x = cz; czv[2].y = sz;
    hsc(theta*g3, &sz, &cz); czv[3].x = cz; czv[3].y = sz; }

  // state: amp n = 4*l + k; s[k] = (re, im) packed
  v2f s[4];
#pragma unroll
  for (int k = 0; k < 4; ++k) { s[k].x = 0.f; s[k].y = 0.f; }
  if (l0) s[0].x = 1.f;

  v2f h1v[5];
#pragma unroll
  for (int j = 0; j < 5; ++j) { h1v[j].x = 0.f; h1v[j].y = 0.f; }
  const float* swl = sw + 5 * l * 784;

  float a0, a1, a2, a3, a4;
  v2f WcA, WcB, WnA, WnB;
  v2f npA, npB;
  v2f pdA, pdB;                                  // pending readout (0-seeded)
  pdA.x = 0.f; pdA.y = 0.f; pdB.x = 0.f; pdB.y = 0.f;
  int pdWin = 0;

  // ================= main rows: wi = 0..12 (h = 4 always) =================
#pragma unroll 1
  for (int wi = 0; wi < 13; ++wi) {
    const float* rp = img + (2 * wi) * 28;
    const float* pA = rp + offA;
    const float* pB = rp + offB;

    // peel wj = 0: direct load + build only (prev row's pending carries over)
    {
      v4f Ac = loadu4(pA);
      v4f Bc = loadu4(pB);
      SEL_MAIN;
      build_gate(a0, a1, a2, a3, a4, WcA, WcB);
    }

    // prefetch window 1
    v4f An = loadu4(pA + 2);
    v4f Bn = loadu4(pB + 2);

    // hot loop: wj = 1..12 — branch-free; unroll 4.
    // Body: BF_LOAD(wj-2) || build(wj) || apply(wj-1) || BF_USE(wj-2).
#pragma unroll 4
    for (int wj = 1; wj <= 12; ++wj) {
      BF_LOAD;                                    // LDS reads, consumed at bottom
      v4f Ac = An, Bc = Bn;
      const int jn = (wj < 12) ? 2 * (wj + 1) : 24;   // clamped dummy on last iter
      An = loadu4(pA + jn);
      Bn = loadu4(pB + jn);
      SEL_MAIN;
      build_gate(a0, a1, a2, a3, a4, WnA, WnB);
      APPLY_Z;                                   // window wj-1 -> np
      BF_USE;                                    // window wj-2 (or older)
      SHIFT_PEND(wi * 14 + wj - 1);
      ROTATE_W;
    }

    // peel wj = 13: w=2 window (cols 26,27)
    {
      v2f C0 = *(const v2f*)(rp + (l1 ? 56 : 0)  + 26);
      v2f C1 = *(const v2f*)(rp + (l1 ? 84 : 28) + 26);
      v2f C2 = *(const v2f*)(rp + (l1 ? 84 : 56) + 26);
      a0 = l0 ? C0.x : (l1 ? C0.y : 0.f);
      a1 = l0 ? C0.y : (l1 ? C1.x : 0.f);
      a2 = l0 ? C1.x : (l1 ? C1.y : 0.f);
      a3 = l0 ? C1.y : 0.f;
      a4 = l0 ? C2.x : 0.f;
      build_gate(a0, a1, a2, a3, a4, WnA, WnB);
    }
    APPLY_Z;                                     // window 12
    BF_FOLD;                                     // window 11
    SHIFT_PEND(wi * 14 + 12);
    ROTATE_W;
    APPLY_Z;                                     // window 13
    BF_FOLD;                                     // window 12
    SHIFT_PEND(wi * 14 + 13);
  }

  // ================= tail row: wi = 13 (h = 2, i = 26) =================
  {
    const float* pA = img + 728 + (l1 ? 28 : 0);  // row 26 (+1 for l1)
    const float* pB = img + 756;                  // row 27

    // peel wj = 0
    {
      v4f Ac = loadu4(pA);
      v4f Bc = loadu4(pB);
      SEL_TAIL;
      build_gate(a0, a1, a2, a3, a4, WcA, WcB);
    }

    v4f An = loadu4(pA + 2);
    v4f Bn = loadu4(pB + 2);

#pragma unroll 4
    for (int wj = 1; wj <= 12; ++wj) {
      BF_LOAD;
      v4f Ac = An, Bc = Bn;
      const int jn = (wj < 12) ? 2 * (wj + 1) : 24;
      An = loadu4(pA + jn);
      Bn = loadu4(pB + jn);
      SEL_TAIL;
      build_gate(a0, a1, a2, a3, a4, WnA, WnB);
      APPLY_Z;
      BF_USE;
      SHIFT_PEND(182 + wj - 1);
      ROTATE_W;
    }

    // peel wj = 13: 2x2 window (rows 26,27 cols 26,27), l0 only
    {
      v2f D0 = *(const v2f*)(img + 26 * 28 + 26);
      v2f D1 = *(const v2f*)(img + 27 * 28 + 26);
      a0 = l0 ? D0.x : 0.f;
      a1 = l0 ? D0.y : 0.f;
      a2 = l0 ? D1.x : 0.f;
      a3 = l0 ? D1.y : 0.f;
      a4 = 0.f;
      build_gate(a0, a1, a2, a3, a4, WnA, WnB);
    }
    APPLY_Z;                                     // window 194
    BF_FOLD;                                     // window 193
    SHIFT_PEND(182 + 12);
    ROTATE_W;
    APPLY_Z;                                     // window 195
    BF_FOLD;                                     // window 194
    SHIFT_PEND(182 + 13);
  }

  // drain the pipeline: fold window 195
  BF_FOLD;

  // ---- epilogue: bias + leaky relu + fc2, reduce over group ----
  float pa = 0.f, pb = 0.f;
#pragma unroll
  for (int j = 0; j < 5; ++j) {
    const int r = 5 * l + j;
    float v = h1v[j].x + h1v[j].y + fc1_b[r];
    v = (v > 0.f) ? v : 0.1f * v;
    pa = fmaf(fc2_w[r],      v, pa);
    pb = fmaf(fc2_w[20 + r], v, pb);
  }
  pa += dppf<QP_XOR1>(pa); pa += dppf<QP_XOR2>(pa);
  pb += dppf<QP_XOR1>(pb); pb += dppf<QP_XOR2>(pb);
  if (l0) {
    float2 res; res.x = pa + fc2_b[0]; res.y = pb + fc2_b[1];
    *(float2*)(out + (size_t)b * 2) = res;
  }
}

extern "C" void kernel_launch(void* const* d_in, const int* in_sizes, int n_in,
                              void* d_out, int out_size, void* d_ws, size_t ws_size,
                              hipStream_t stream) {
  const float* x      = (const float*)d_in[0];
  const float* crz_t  = (const float*)d_in[1];
  const float* ry_t   = (const float*)d_in[2];
  const float* fc1_w  = (const float*)d_in[3];
  const float* fc1_b  = (const float*)d_in[4];
  const float* fc2_w  = (const float*)d_in[5];
  const float* fc2_b  = (const float*)d_in[6];
  float* out = (float*)d_out;
  const int B = in_sizes[0] / 784;
  const int grid = (B * 4 + 255) / 256;
  quanv_kernel<<<grid, 256, 0, stream>>>(x, crz_t, ry_t, fc1_w, fc1_b,
                                         fc2_w, fc2_b, out, B);
}